// Round 1
// baseline (1009.198 us; speedup 1.0000x reference)
//
#include <hip/hip_runtime.h>
#include <math.h>

#define TN 16
#define EPS 1e-12f

// ws layout (float offsets)
#define OFF_W1T 0        // [128][128]  se3(weight)^T
#define OFF_W2T 16384    // [128][128]  se3(cross_weight)^T
#define OFF_W3T 32768    // [256][128]  se3(crossfc_weight)^T
#define OFF_VDT 65536    // [128][128]  vsdir^T
#define OFF_SVT 81920    // [128][128]  sv_W^T
#define OFF_VST 98304    // [128][128]  vs_W^T
#define OFF_SST 114688   // [128][128]  ss_W^T
#define OFF_VDR 131072   // [128]       rowsum(vsdir)

__device__ __forceinline__ float block_sum_256(float v, float* red) {
  const int t = threadIdx.x;
  red[t] = v;
  __syncthreads();
  for (int s = 128; s > 0; s >>= 1) {
    if (t < s) red[t] += red[t + s];
    __syncthreads();
  }
  float r = red[0];
  __syncthreads();
  return r;
}

__device__ __forceinline__ float red32(float v) {
#pragma unroll
  for (int k = 16; k > 0; k >>= 1) v += __shfl_xor(v, k, 32);
  return v;
}

__global__ __launch_bounds__(256) void k_pre(
    const float* __restrict__ weight, const float* __restrict__ sv_W,
    const float* __restrict__ cross_w, const float* __restrict__ crossfc_w,
    const float* __restrict__ vsdir_w, const float* __restrict__ vs_W,
    const float* __restrict__ ss_W, float* __restrict__ ws) {
  __shared__ float red[256];
  const int o = blockIdx.x;   // 128 blocks, one per output channel row
  const int t = threadIdx.x;  // 256

  float s1 = block_sum_256((t < 127) ? weight[o * 127 + t] : 0.f, red);
  if (t < 128) ws[OFF_W1T + t * 128 + o] = (t < 127) ? weight[o * 127 + t] : 1.f - s1;

  float s2 = block_sum_256((t < 127) ? cross_w[o * 127 + t] : 0.f, red);
  if (t < 128) ws[OFF_W2T + t * 128 + o] = (t < 127) ? cross_w[o * 127 + t] : 1.f - s2;

  float s3 = block_sum_256((t < 255) ? crossfc_w[o * 255 + t] : 0.f, red);
  ws[OFF_W3T + t * 128 + o] = (t < 255) ? crossfc_w[o * 255 + t] : 1.f - s3;

  float s4 = block_sum_256((t < 128) ? vsdir_w[o * 128 + t] : 0.f, red);
  if (t == 0) ws[OFF_VDR + o] = s4;

  if (t < 128) {
    ws[OFF_VDT + t * 128 + o] = vsdir_w[o * 128 + t];
    ws[OFF_SVT + t * 128 + o] = sv_W[o * 128 + t];
    ws[OFF_VST + t * 128 + o] = vs_W[o * 128 + t];
    ws[OFF_SST + t * 128 + o] = ss_W[o * 128 + t];
  }
}

// K1: v2 = (W1@x - mean)*s2v + mean  -> d_out v-region (stage)
//     full scalar path               -> d_out s-region (final)
__global__ __launch_bounds__(256) void k1(
    const float* __restrict__ v_in, const float* __restrict__ s_in,
    const float* __restrict__ ws,
    const float* __restrict__ sv_b, const float* __restrict__ vs_b,
    const float* __restrict__ ss_b,
    float* __restrict__ v_out, float* __restrict__ s_out) {
  const int t = threadIdx.x;
  const int og = t & 31, jg = t >> 5;     // 32 o-groups x 8 j-groups
  const int j0 = jg * 2, o0 = og * 4;     // thread: 4 channels x 2 columns
  const int b = blockIdx.x >> 8;          // N/TN = 256 tiles per batch
  const int n0 = (blockIdx.x & 255) * TN;

  __shared__ float xt[128][3][TN];
  __shared__ float st[128][TN];
  __shared__ float sft[128][TN];

  const float* __restrict__ W1T = ws + OFF_W1T;
  const float* __restrict__ VDT = ws + OFF_VDT;
  const float* __restrict__ SVT = ws + OFF_SVT;
  const float* __restrict__ VST = ws + OFF_VST;
  const float* __restrict__ SST = ws + OFF_SST;
  const float* __restrict__ VDR = ws + OFF_VDR;

  {
    const float* vb = v_in + (size_t)b * (128 * 3 * 4096) + n0;
    float4* xt4 = (float4*)xt;
    for (int l = t; l < 1536; l += 256) {
      const int c = l / 12, q = l % 12;
      const int v = q >> 2, j4 = q & 3;
      xt4[l] = *(const float4*)(vb + (size_t)(c * 3 + v) * 4096 + j4 * 4);
    }
    const float* sb = s_in + (size_t)b * (128 * 4096) + n0;
    float4* st4 = (float4*)st;
    for (int l = t; l < 512; l += 256) {
      const int c = l >> 2, j4 = l & 3;
      st4[l] = *(const float4*)(sb + (size_t)c * 4096 + j4 * 4);
    }
  }
  __syncthreads();

  float v1[4][3][2] = {};
  float dd[4][3][2] = {};
  float tsv[4][2] = {};
  float tss[4][2] = {};
  float xs[3][2] = {};

#pragma unroll 2
  for (int c = 0; c < 128; ++c) {
    const float4 w1 = *(const float4*)(W1T + c * 128 + o0);
    const float4 wd = *(const float4*)(VDT + c * 128 + o0);
    const float4 wv = *(const float4*)(SVT + c * 128 + o0);
    const float4 wr = *(const float4*)(SST + c * 128 + o0);
    float x[3][2];
#pragma unroll
    for (int v = 0; v < 3; ++v) {
      const float2 p = *(const float2*)&xt[c][v][j0];
      x[v][0] = p.x; x[v][1] = p.y;
      xs[v][0] += p.x; xs[v][1] += p.y;
    }
    const float2 sp = *(const float2*)&st[c][j0];
    const float* w1f = (const float*)&w1;
    const float* wdf = (const float*)&wd;
    const float* wvf = (const float*)&wv;
    const float* wrf = (const float*)&wr;
#pragma unroll
    for (int m = 0; m < 4; ++m) {
#pragma unroll
      for (int v = 0; v < 3; ++v) {
        v1[m][v][0] += w1f[m] * x[v][0];
        v1[m][v][1] += w1f[m] * x[v][1];
        dd[m][v][0] += wdf[m] * x[v][0];
        dd[m][v][1] += wdf[m] * x[v][1];
      }
      tsv[m][0] += wvf[m] * sp.x;
      tsv[m][1] += wvf[m] * sp.y;
      tss[m][0] += wrf[m] * sp.x;
      tss[m][1] += wrf[m] * sp.y;
    }
  }

  // s2v = normalize(sv_W@s + sv_b, axis=channel)
  const float4 svb = *(const float4*)(sv_b + o0);
  const float* svbf = (const float*)&svb;
  float s2v[4][2];
#pragma unroll
  for (int jj = 0; jj < 2; ++jj) {
    float tb[4], nrm = 0.f;
#pragma unroll
    for (int m = 0; m < 4; ++m) { tb[m] = tsv[m][jj] + svbf[m]; nrm += tb[m] * tb[m]; }
    nrm = red32(nrm);
    const float inv = 1.f / fmaxf(sqrtf(nrm), EPS);
#pragma unroll
    for (int m = 0; m < 4; ++m) s2v[m][jj] = tb[m] * inv;
  }

  // v_mean over channels (pre-scaling)
  float vm[3][2];
#pragma unroll
  for (int v = 0; v < 3; ++v)
#pragma unroll
    for (int jj = 0; jj < 2; ++jj) {
      float s = v1[0][v][jj] + v1[1][v][jj] + v1[2][v][jj] + v1[3][v][jj];
      vm[v][jj] = red32(s) * (1.f / 128.f);
    }

  // v2 = (v1 - vm)*s2v + vm; store stage to d_out v-region
  float* vob = v_out + (size_t)b * (128 * 3 * 4096) + n0 + j0;
#pragma unroll
  for (int m = 0; m < 4; ++m)
#pragma unroll
    for (int v = 0; v < 3; ++v) {
      float2 p;
      p.x = (v1[m][v][0] - vm[v][0]) * s2v[m][0] + vm[v][0];
      p.y = (v1[m][v][1] - vm[v][1]) * s2v[m][1] + vm[v][1];
      *(float2*)(vob + (size_t)((o0 + m) * 3 + v) * 4096) = p;
    }

  // ---- scalar path ----
  float xm[3][2];
#pragma unroll
  for (int v = 0; v < 3; ++v) {
    xm[v][0] = xs[v][0] * (1.f / 128.f);
    xm[v][1] = xs[v][1] * (1.f / 128.f);
  }

  const float4 rs = *(const float4*)(VDR + o0);
  const float* rsf = (const float*)&rs;
  float sfv[4][2];
#pragma unroll
  for (int m = 0; m < 4; ++m) {
    const int o = o0 + m;
#pragma unroll
    for (int jj = 0; jj < 2; ++jj) {
      // centered vsdir matmul: (vsdir@x) - rowsum*xmean
      float d0 = dd[m][0][jj] - rsf[m] * xm[0][jj];
      float d1 = dd[m][1][jj] - rsf[m] * xm[1][jj];
      float d2 = dd[m][2][jj] - rsf[m] * xm[2][jj];
      const float inv = 1.f / fmaxf(sqrtf(d0 * d0 + d1 * d1 + d2 * d2), EPS);
      const float x0 = xt[o][0][j0 + jj] - xm[0][jj];
      const float x1 = xt[o][1][j0 + jj] - xm[1][jj];
      const float x2 = xt[o][2][j0 + jj] - xm[2][jj];
      sfv[m][jj] = (x0 * d0 + x1 * d1 + x2 * d2) * inv;
    }
  }
#pragma unroll
  for (int jj = 0; jj < 2; ++jj) {
    float nrm = sfv[0][jj] * sfv[0][jj] + sfv[1][jj] * sfv[1][jj] +
                sfv[2][jj] * sfv[2][jj] + sfv[3][jj] * sfv[3][jj];
    nrm = red32(nrm);
    const float inv = 1.f / fmaxf(sqrtf(nrm), EPS);
#pragma unroll
    for (int m = 0; m < 4; ++m) sft[o0 + m][j0 + jj] = sfv[m][jj] * inv;
  }
  __syncthreads();

  float sacc[4][2] = {};
#pragma unroll 4
  for (int c = 0; c < 128; ++c) {
    const float4 wv2 = *(const float4*)(VST + c * 128 + o0);
    const float* wf = (const float*)&wv2;
    const float2 f = *(const float2*)&sft[c][j0];
#pragma unroll
    for (int m = 0; m < 4; ++m) {
      sacc[m][0] += wf[m] * f.x;
      sacc[m][1] += wf[m] * f.y;
    }
  }
  const float4 vsb = *(const float4*)(vs_b + o0);
  const float4 ssb = *(const float4*)(ss_b + o0);
  const float* vsbf = (const float*)&vsb;
  const float* ssbf = (const float*)&ssb;
  float* sob = s_out + (size_t)b * (128 * 4096) + n0 + j0;
#pragma unroll
  for (int m = 0; m < 4; ++m) {
    float2 p;
    p.x = sacc[m][0] + vsbf[m] + tss[m][0] + ssbf[m];
    p.y = sacc[m][1] + vsbf[m] + tss[m][1] + ssbf[m];
    *(float2*)(sob + (size_t)(o0 + m) * 4096) = p;
  }
}

// K2: v_dual = W2@x (recomputed), cross branch, crossfc -> final v_out (in place)
__global__ __launch_bounds__(256) void k2(
    const float* __restrict__ v_in, const float* __restrict__ ws,
    float* __restrict__ v_out) {
  const int t = threadIdx.x;
  const int og = t & 31, jg = t >> 5;
  const int j0 = jg * 2, o0 = og * 4;
  const int b = blockIdx.x >> 8;
  const int n0 = (blockIdx.x & 255) * TN;

  __shared__ float xt[128][3][TN];   // x, later reused for cr
  __shared__ float v2t[128][3][TN];

  const float* __restrict__ W2T = ws + OFF_W2T;
  const float* __restrict__ W3T = ws + OFF_W3T;

  const float* vb = v_in + (size_t)b * (128 * 3 * 4096) + n0;
  float* vob = v_out + (size_t)b * (128 * 3 * 4096) + n0;
  {
    float4* xt4 = (float4*)xt;
    float4* v2t4 = (float4*)v2t;
    for (int l = t; l < 1536; l += 256) {
      const int c = l / 12, q = l % 12;
      const int v = q >> 2, j4 = q & 3;
      const size_t off = (size_t)(c * 3 + v) * 4096 + j4 * 4;
      xt4[l] = *(const float4*)(vb + off);
      v2t4[l] = *(const float4*)(vob + off);
    }
  }
  __syncthreads();

  float vd[4][3][2] = {};
  float v2s[3][2] = {};
#pragma unroll 2
  for (int c = 0; c < 128; ++c) {
    const float4 w2 = *(const float4*)(W2T + c * 128 + o0);
    const float* wf = (const float*)&w2;
    float x[3][2];
#pragma unroll
    for (int v = 0; v < 3; ++v) {
      const float2 px = *(const float2*)&xt[c][v][j0];
      const float2 pv = *(const float2*)&v2t[c][v][j0];
      x[v][0] = px.x; x[v][1] = px.y;
      v2s[v][0] += pv.x; v2s[v][1] += pv.y;
    }
#pragma unroll
    for (int m = 0; m < 4; ++m)
#pragma unroll
      for (int v = 0; v < 3; ++v) {
        vd[m][v][0] += wf[m] * x[v][0];
        vd[m][v][1] += wf[m] * x[v][1];
      }
  }

  float dm[3][2], v2m[3][2];
#pragma unroll
  for (int v = 0; v < 3; ++v)
#pragma unroll
    for (int jj = 0; jj < 2; ++jj) {
      float s = vd[0][v][jj] + vd[1][v][jj] + vd[2][v][jj] + vd[3][v][jj];
      dm[v][jj] = red32(s) * (1.f / 128.f);
      v2m[v][jj] = v2s[v][jj] * (1.f / 128.f);
    }

  float an[4][2];
#pragma unroll
  for (int m = 0; m < 4; ++m)
#pragma unroll
    for (int jj = 0; jj < 2; ++jj) {
      float a0 = vd[m][0][jj] - dm[0][jj];
      float a1 = vd[m][1][jj] - dm[1][jj];
      float a2 = vd[m][2][jj] - dm[2][jj];
      vd[m][0][jj] = a0; vd[m][1][jj] = a1; vd[m][2][jj] = a2;
      an[m][jj] = sqrtf(a0 * a0 + a1 * a1 + a2 * a2);
    }
  float cninv[2];
#pragma unroll
  for (int jj = 0; jj < 2; ++jj) {
    float s = an[0][jj] * an[0][jj] + an[1][jj] * an[1][jj] +
              an[2][jj] * an[2][jj] + an[3][jj] * an[3][jj];
    s = red32(s);
    cninv[jj] = 1.f / fmaxf(sqrtf(s), EPS);
  }

  float cr[4][3][2];
#pragma unroll
  for (int m = 0; m < 4; ++m) {
    const int o = o0 + m;
#pragma unroll
    for (int jj = 0; jj < 2; ++jj) {
      // ahat = (a / max(|a|,eps)) * (|a| / max(||an||_ch,eps))
      const float sc = (1.f / fmaxf(an[m][jj], EPS)) * (an[m][jj] * cninv[jj]);
      const float h0 = vd[m][0][jj] * sc;
      const float h1 = vd[m][1][jj] * sc;
      const float h2 = vd[m][2][jj] * sc;
      const float w0 = v2t[o][0][j0 + jj];
      const float w1 = v2t[o][1][j0 + jj];
      const float w2 = v2t[o][2][j0 + jj];
      const float g0 = w0 - v2m[0][jj];
      const float g1 = w1 - v2m[1][jj];
      const float g2 = w2 - v2m[2][jj];
      cr[m][0][jj] = h1 * g2 - h2 * g1 + w0;
      cr[m][1][jj] = h2 * g0 - h0 * g2 + w1;
      cr[m][2][jj] = h0 * g1 - h1 * g0 + w2;
    }
  }
  __syncthreads();  // all xt reads done before overwrite
#pragma unroll
  for (int m = 0; m < 4; ++m)
#pragma unroll
    for (int v = 0; v < 3; ++v) {
      xt[o0 + m][v][j0] = cr[m][v][0];
      xt[o0 + m][v][j0 + 1] = cr[m][v][1];
    }
  __syncthreads();

  float acc[4][3][2] = {};
#pragma unroll 2
  for (int c = 0; c < 128; ++c) {
    const float4 wa = *(const float4*)(W3T + c * 128 + o0);
    const float4 wb = *(const float4*)(W3T + (128 + c) * 128 + o0);
    const float* waf = (const float*)&wa;
    const float* wbf = (const float*)&wb;
    float cx[3][2], vx[3][2];
#pragma unroll
    for (int v = 0; v < 3; ++v) {
      const float2 pc = *(const float2*)&xt[c][v][j0];
      const float2 pv = *(const float2*)&v2t[c][v][j0];
      cx[v][0] = pc.x; cx[v][1] = pc.y;
      vx[v][0] = pv.x; vx[v][1] = pv.y;
    }
#pragma unroll
    for (int m = 0; m < 4; ++m)
#pragma unroll
      for (int v = 0; v < 3; ++v) {
        acc[m][v][0] += waf[m] * cx[v][0] + wbf[m] * vx[v][0];
        acc[m][v][1] += waf[m] * cx[v][1] + wbf[m] * vx[v][1];
      }
  }
#pragma unroll
  for (int m = 0; m < 4; ++m)
#pragma unroll
    for (int v = 0; v < 3; ++v) {
      float2 p;
      p.x = acc[m][v][0];
      p.y = acc[m][v][1];
      *(float2*)(vob + (size_t)((o0 + m) * 3 + v) * 4096 + j0) = p;
    }
}

extern "C" void kernel_launch(void* const* d_in, const int* in_sizes, int n_in,
                              void* d_out, int out_size, void* d_ws, size_t ws_size,
                              hipStream_t stream) {
  const float* v_in      = (const float*)d_in[0];
  const float* s_in      = (const float*)d_in[1];
  const float* weight    = (const float*)d_in[2];
  const float* sv_W      = (const float*)d_in[3];
  const float* sv_b      = (const float*)d_in[4];
  const float* cross_w   = (const float*)d_in[5];
  const float* crossfc_w = (const float*)d_in[6];
  const float* vsdir_w   = (const float*)d_in[7];
  const float* vs_W      = (const float*)d_in[8];
  const float* vs_b      = (const float*)d_in[9];
  const float* ss_W      = (const float*)d_in[10];
  const float* ss_b      = (const float*)d_in[11];

  float* out = (float*)d_out;
  float* v_out = out;                                  // [16][128][3][4096]
  float* s_out = out + (size_t)16 * 128 * 3 * 4096;    // [16][128][4096]
  float* ws = (float*)d_ws;                            // needs ~525 KB

  hipLaunchKernelGGL(k_pre, dim3(128), dim3(256), 0, stream,
                     weight, sv_W, cross_w, crossfc_w, vsdir_w, vs_W, ss_W, ws);
  hipLaunchKernelGGL(k1, dim3(4096), dim3(256), 0, stream,
                     v_in, s_in, ws, sv_b, vs_b, ss_b, v_out, s_out);
  hipLaunchKernelGGL(k2, dim3(4096), dim3(256), 0, stream,
                     v_in, ws, v_out);
}

// Round 2
// 918.125 us; speedup vs baseline: 1.0992x; 1.0992x over previous
//
#include <hip/hip_runtime.h>
#include <math.h>

#define EPS 1e-12f

// ws layout (float offsets). All weight matrices stored transposed+swizzled:
//   WT[c][og][m] = W_se3[og + 32*m][c]   (so a thread with lane og loads float4 at c*128+og*4)
#define OFF_W1T 0        // [128][128]  se3(weight)^T
#define OFF_W2T 16384    // [128][128]  se3(cross_weight)^T
#define OFF_W3T 32768    // [256][128]  se3(crossfc_weight)^T
#define OFF_VDT 65536    // [128][128]  vsdir^T
#define OFF_SVT 81920    // [128][128]  sv_W^T
#define OFF_VST 98304    // [128][128]  vs_W^T
#define OFF_SST 114688   // [128][128]  ss_W^T
#define OFF_VDR 131072   // [128]       rowsum(vsdir), swizzled [og*4+m]

__device__ __forceinline__ float block_sum_256(float v, float* red) {
  const int t = threadIdx.x;
  red[t] = v;
  __syncthreads();
  for (int s = 128; s > 0; s >>= 1) {
    if (t < s) red[t] += red[t + s];
    __syncthreads();
  }
  float r = red[0];
  __syncthreads();
  return r;
}

__device__ __forceinline__ float red32(float v) {
#pragma unroll
  for (int k = 16; k > 0; k >>= 1) v += __shfl_xor(v, k, 32);
  return v;
}

__global__ __launch_bounds__(256) void k_pre(
    const float* __restrict__ weight, const float* __restrict__ sv_W,
    const float* __restrict__ cross_w, const float* __restrict__ crossfc_w,
    const float* __restrict__ vsdir_w, const float* __restrict__ vs_W,
    const float* __restrict__ ss_W, float* __restrict__ ws) {
  __shared__ float red[256];
  const int o = blockIdx.x;   // 128 blocks, one per output-channel row
  const int t = threadIdx.x;  // 256
  const int sw = (o & 31) * 4 + (o >> 5);  // swizzled column slot for row o

  float s1 = block_sum_256((t < 127) ? weight[o * 127 + t] : 0.f, red);
  if (t < 128) ws[OFF_W1T + t * 128 + sw] = (t < 127) ? weight[o * 127 + t] : 1.f - s1;

  float s2 = block_sum_256((t < 127) ? cross_w[o * 127 + t] : 0.f, red);
  if (t < 128) ws[OFF_W2T + t * 128 + sw] = (t < 127) ? cross_w[o * 127 + t] : 1.f - s2;

  float s3 = block_sum_256((t < 255) ? crossfc_w[o * 255 + t] : 0.f, red);
  ws[OFF_W3T + t * 128 + sw] = (t < 255) ? crossfc_w[o * 255 + t] : 1.f - s3;

  float s4 = block_sum_256((t < 128) ? vsdir_w[o * 128 + t] : 0.f, red);
  if (t == 0) ws[OFF_VDR + sw] = s4;

  if (t < 128) {
    ws[OFF_VDT + t * 128 + sw] = vsdir_w[o * 128 + t];
    ws[OFF_SVT + t * 128 + sw] = sv_W[o * 128 + t];
    ws[OFF_VST + t * 128 + sw] = vs_W[o * 128 + t];
    ws[OFF_SST + t * 128 + sw] = ss_W[o * 128 + t];
  }
}

// Fused kernel: entire op for one (b, 16-column tile).
// Thread map: og = t&31, jg = t>>5; channels o = og + 32*m (m=0..3), cols j0 = jg*2 (+0,+1).
// Diagonal LDS accesses: lane stride 51 floats -> 19*og mod 32 -> all 32 banks (conflict-free).
__global__ __launch_bounds__(256) void k_main(
    const float* __restrict__ v_in, const float* __restrict__ s_in,
    const float* __restrict__ ws,
    const float* __restrict__ sv_b, const float* __restrict__ vs_b,
    const float* __restrict__ ss_b,
    float* __restrict__ v_out, float* __restrict__ s_out) {
  const int t = threadIdx.x;
  const int og = t & 31, jg = t >> 5;
  const int j0 = jg * 2;
  const int b = blockIdx.x >> 8;
  const int n0 = (blockIdx.x & 255) * 16;

  __shared__ float xt[128][3][17];   // x; later reused for cr
  __shared__ float st[128][17];      // s; later reused for sft (normalized s_from_v)
  __shared__ float v2t[128][3][17];  // v2 (post-scaling v_out stage)

  const float* __restrict__ W1T = ws + OFF_W1T + og * 4;
  const float* __restrict__ W2T = ws + OFF_W2T + og * 4;
  const float* __restrict__ W3Ta = ws + OFF_W3T + og * 4;
  const float* __restrict__ W3Tb = ws + OFF_W3T + 128 * 128 + og * 4;
  const float* __restrict__ VDT = ws + OFF_VDT + og * 4;
  const float* __restrict__ SVT = ws + OFF_SVT + og * 4;
  const float* __restrict__ VST = ws + OFF_VST + og * 4;
  const float* __restrict__ SST = ws + OFF_SST + og * 4;

  // ---- stage x and s tiles into LDS (padded scalar scatter) ----
  {
    const float* vb = v_in + (size_t)b * (128 * 3 * 4096) + n0;
    for (int l = t; l < 1536; l += 256) {
      const int c = l / 12, q = l % 12;
      const int v = q >> 2, j4 = (q & 3) * 4;
      const float4 f = *(const float4*)(vb + (size_t)(c * 3 + v) * 4096 + j4);
      xt[c][v][j4] = f.x; xt[c][v][j4 + 1] = f.y;
      xt[c][v][j4 + 2] = f.z; xt[c][v][j4 + 3] = f.w;
    }
    const float* sb = s_in + (size_t)b * (128 * 4096) + n0;
    for (int l = t; l < 512; l += 256) {
      const int c = l >> 2, j4 = (l & 3) * 4;
      const float4 f = *(const float4*)(sb + (size_t)c * 4096 + j4);
      st[c][j4] = f.x; st[c][j4 + 1] = f.y;
      st[c][j4 + 2] = f.z; st[c][j4 + 3] = f.w;
    }
  }
  __syncthreads();

  // ---- main c-loop: v1 = W1@x, vd = W2@x, dd = vsdir@x, tsv = sv@s, tss = ss@s, xs = sum(x) ----
  float v1[4][3][2] = {};
  float vd[4][3][2] = {};
  float dd[4][3][2] = {};
  float tsv[4][2] = {};
  float tss[4][2] = {};
  float xs[3][2] = {};

#pragma unroll 2
  for (int c = 0; c < 128; ++c) {
    const float4 w1 = *(const float4*)(W1T + c * 128);
    const float4 w2 = *(const float4*)(W2T + c * 128);
    const float4 wd = *(const float4*)(VDT + c * 128);
    const float4 wv = *(const float4*)(SVT + c * 128);
    const float4 wr = *(const float4*)(SST + c * 128);
    const float* w1f = (const float*)&w1;
    const float* w2f = (const float*)&w2;
    const float* wdf = (const float*)&wd;
    const float* wvf = (const float*)&wv;
    const float* wrf = (const float*)&wr;
    float x[3][2];
#pragma unroll
    for (int v = 0; v < 3; ++v) {
      x[v][0] = xt[c][v][j0];
      x[v][1] = xt[c][v][j0 + 1];
      xs[v][0] += x[v][0]; xs[v][1] += x[v][1];
    }
    const float sp0 = st[c][j0], sp1 = st[c][j0 + 1];
#pragma unroll
    for (int m = 0; m < 4; ++m) {
#pragma unroll
      for (int v = 0; v < 3; ++v) {
        v1[m][v][0] += w1f[m] * x[v][0];
        v1[m][v][1] += w1f[m] * x[v][1];
        vd[m][v][0] += w2f[m] * x[v][0];
        vd[m][v][1] += w2f[m] * x[v][1];
        dd[m][v][0] += wdf[m] * x[v][0];
        dd[m][v][1] += wdf[m] * x[v][1];
      }
      tsv[m][0] += wvf[m] * sp0;
      tsv[m][1] += wvf[m] * sp1;
      tss[m][0] += wrf[m] * sp0;
      tss[m][1] += wrf[m] * sp1;
    }
  }

  // ---- s2v = normalize(sv@s + sv_b, ch) ----
  float svb[4], vsb[4], ssb[4];
#pragma unroll
  for (int m = 0; m < 4; ++m) {
    svb[m] = sv_b[og + 32 * m];
    vsb[m] = vs_b[og + 32 * m];
    ssb[m] = ss_b[og + 32 * m];
  }
  float s2v[4][2];
#pragma unroll
  for (int jj = 0; jj < 2; ++jj) {
    float tb[4], nrm = 0.f;
#pragma unroll
    for (int m = 0; m < 4; ++m) { tb[m] = tsv[m][jj] + svb[m]; nrm += tb[m] * tb[m]; }
    nrm = red32(nrm);
    const float inv = 1.f / fmaxf(sqrtf(nrm), EPS);
#pragma unroll
    for (int m = 0; m < 4; ++m) s2v[m][jj] = tb[m] * inv;
  }

  // ---- v2 = (v1 - vmean)*s2v + vmean (kept in regs) ----
  float vm[3][2];
#pragma unroll
  for (int v = 0; v < 3; ++v)
#pragma unroll
    for (int jj = 0; jj < 2; ++jj) {
      float s = v1[0][v][jj] + v1[1][v][jj] + v1[2][v][jj] + v1[3][v][jj];
      vm[v][jj] = red32(s) * (1.f / 128.f);
    }
  float v2[4][3][2];
#pragma unroll
  for (int m = 0; m < 4; ++m)
#pragma unroll
    for (int v = 0; v < 3; ++v)
#pragma unroll
      for (int jj = 0; jj < 2; ++jj)
        v2[m][v][jj] = (v1[m][v][jj] - vm[v][jj]) * s2v[m][jj] + vm[v][jj];

  // ---- scalar path: s_from_v (pre-normalize), diagonal x reads ----
  float xm[3][2];
#pragma unroll
  for (int v = 0; v < 3; ++v) {
    xm[v][0] = xs[v][0] * (1.f / 128.f);
    xm[v][1] = xs[v][1] * (1.f / 128.f);
  }
  const float4 rs = *(const float4*)(ws + OFF_VDR + og * 4);
  const float* rsf = (const float*)&rs;
  float sfv[4][2];
#pragma unroll
  for (int m = 0; m < 4; ++m) {
    const int o = og + 32 * m;
#pragma unroll
    for (int jj = 0; jj < 2; ++jj) {
      float d0 = dd[m][0][jj] - rsf[m] * xm[0][jj];
      float d1 = dd[m][1][jj] - rsf[m] * xm[1][jj];
      float d2 = dd[m][2][jj] - rsf[m] * xm[2][jj];
      const float inv = 1.f / fmaxf(sqrtf(d0 * d0 + d1 * d1 + d2 * d2), EPS);
      const float x0 = xt[o][0][j0 + jj] - xm[0][jj];
      const float x1 = xt[o][1][j0 + jj] - xm[1][jj];
      const float x2 = xt[o][2][j0 + jj] - xm[2][jj];
      sfv[m][jj] = (x0 * d0 + x1 * d1 + x2 * d2) * inv;
    }
  }
  float sfn[4][2];
#pragma unroll
  for (int jj = 0; jj < 2; ++jj) {
    float nrm = sfv[0][jj] * sfv[0][jj] + sfv[1][jj] * sfv[1][jj] +
                sfv[2][jj] * sfv[2][jj] + sfv[3][jj] * sfv[3][jj];
    nrm = red32(nrm);
    const float inv = 1.f / fmaxf(sqrtf(nrm), EPS);
#pragma unroll
    for (int m = 0; m < 4; ++m) sfn[m][jj] = sfv[m][jj] * inv;
  }

  // ---- cross branch (all regs) ----
  float dm[3][2], v2m[3][2];
#pragma unroll
  for (int v = 0; v < 3; ++v)
#pragma unroll
    for (int jj = 0; jj < 2; ++jj) {
      float s = vd[0][v][jj] + vd[1][v][jj] + vd[2][v][jj] + vd[3][v][jj];
      dm[v][jj] = red32(s) * (1.f / 128.f);
      float s2 = v2[0][v][jj] + v2[1][v][jj] + v2[2][v][jj] + v2[3][v][jj];
      v2m[v][jj] = red32(s2) * (1.f / 128.f);
    }
  float an[4][2];
#pragma unroll
  for (int m = 0; m < 4; ++m)
#pragma unroll
    for (int jj = 0; jj < 2; ++jj) {
      float a0 = vd[m][0][jj] - dm[0][jj];
      float a1 = vd[m][1][jj] - dm[1][jj];
      float a2 = vd[m][2][jj] - dm[2][jj];
      vd[m][0][jj] = a0; vd[m][1][jj] = a1; vd[m][2][jj] = a2;
      an[m][jj] = sqrtf(a0 * a0 + a1 * a1 + a2 * a2);
    }
  float cninv[2];
#pragma unroll
  for (int jj = 0; jj < 2; ++jj) {
    float s = an[0][jj] * an[0][jj] + an[1][jj] * an[1][jj] +
              an[2][jj] * an[2][jj] + an[3][jj] * an[3][jj];
    s = red32(s);
    cninv[jj] = 1.f / fmaxf(sqrtf(s), EPS);
  }
  float cr[4][3][2];
#pragma unroll
  for (int m = 0; m < 4; ++m)
#pragma unroll
    for (int jj = 0; jj < 2; ++jj) {
      const float sc = (1.f / fmaxf(an[m][jj], EPS)) * (an[m][jj] * cninv[jj]);
      const float h0 = vd[m][0][jj] * sc;
      const float h1 = vd[m][1][jj] * sc;
      const float h2 = vd[m][2][jj] * sc;
      const float w0 = v2[m][0][jj], w1 = v2[m][1][jj], w2 = v2[m][2][jj];
      const float g0 = w0 - v2m[0][jj];
      const float g1 = w1 - v2m[1][jj];
      const float g2 = w2 - v2m[2][jj];
      cr[m][0][jj] = h1 * g2 - h2 * g1 + w0;
      cr[m][1][jj] = h2 * g0 - h0 * g2 + w1;
      cr[m][2][jj] = h0 * g1 - h1 * g0 + w2;
    }

  __syncthreads();  // all xt/st reads above complete before overwrite

  // ---- stage sft, cr, v2 into LDS (conflict-free diagonal writes) ----
#pragma unroll
  for (int m = 0; m < 4; ++m) {
    const int o = og + 32 * m;
    st[o][j0] = sfn[m][0];
    st[o][j0 + 1] = sfn[m][1];
#pragma unroll
    for (int v = 0; v < 3; ++v) {
      xt[o][v][j0] = cr[m][v][0];
      xt[o][v][j0 + 1] = cr[m][v][1];
      v2t[o][v][j0] = v2[m][v][0];
      v2t[o][v][j0 + 1] = v2[m][v][1];
    }
  }
  __syncthreads();

  // ---- epilogue c-loop: v_out = W3@[cr;v2], s_from_v = vs@sft ----
  float acc[4][3][2] = {};
  float sacc[4][2] = {};
#pragma unroll 2
  for (int c = 0; c < 128; ++c) {
    const float4 wa = *(const float4*)(W3Ta + c * 128);
    const float4 wb = *(const float4*)(W3Tb + c * 128);
    const float4 wv2 = *(const float4*)(VST + c * 128);
    const float* waf = (const float*)&wa;
    const float* wbf = (const float*)&wb;
    const float* wvf = (const float*)&wv2;
    float cx[3][2], vx[3][2];
#pragma unroll
    for (int v = 0; v < 3; ++v) {
      cx[v][0] = xt[c][v][j0];  cx[v][1] = xt[c][v][j0 + 1];
      vx[v][0] = v2t[c][v][j0]; vx[v][1] = v2t[c][v][j0 + 1];
    }
    const float f0 = st[c][j0], f1 = st[c][j0 + 1];
#pragma unroll
    for (int m = 0; m < 4; ++m) {
#pragma unroll
      for (int v = 0; v < 3; ++v) {
        acc[m][v][0] += waf[m] * cx[v][0] + wbf[m] * vx[v][0];
        acc[m][v][1] += waf[m] * cx[v][1] + wbf[m] * vx[v][1];
      }
      sacc[m][0] += wvf[m] * f0;
      sacc[m][1] += wvf[m] * f1;
    }
  }

  // ---- global stores ----
  float* vob = v_out + (size_t)b * (128 * 3 * 4096) + n0 + j0;
  float* sob = s_out + (size_t)b * (128 * 4096) + n0 + j0;
#pragma unroll
  for (int m = 0; m < 4; ++m) {
    const int o = og + 32 * m;
#pragma unroll
    for (int v = 0; v < 3; ++v) {
      float2 p;
      p.x = acc[m][v][0];
      p.y = acc[m][v][1];
      *(float2*)(vob + (size_t)(o * 3 + v) * 4096) = p;
    }
    float2 q;
    q.x = sacc[m][0] + vsb[m] + tss[m][0] + ssb[m];
    q.y = sacc[m][1] + vsb[m] + tss[m][1] + ssb[m];
    *(float2*)(sob + (size_t)o * 4096) = q;
  }
}

extern "C" void kernel_launch(void* const* d_in, const int* in_sizes, int n_in,
                              void* d_out, int out_size, void* d_ws, size_t ws_size,
                              hipStream_t stream) {
  const float* v_in      = (const float*)d_in[0];
  const float* s_in      = (const float*)d_in[1];
  const float* weight    = (const float*)d_in[2];
  const float* sv_W      = (const float*)d_in[3];
  const float* sv_b      = (const float*)d_in[4];
  const float* cross_w   = (const float*)d_in[5];
  const float* crossfc_w = (const float*)d_in[6];
  const float* vsdir_w   = (const float*)d_in[7];
  const float* vs_W      = (const float*)d_in[8];
  const float* vs_b      = (const float*)d_in[9];
  const float* ss_W      = (const float*)d_in[10];
  const float* ss_b      = (const float*)d_in[11];

  float* out = (float*)d_out;
  float* v_out = out;                                  // [16][128][3][4096]
  float* s_out = out + (size_t)16 * 128 * 3 * 4096;    // [16][128][4096]
  float* ws = (float*)d_ws;                            // ~525 KB

  hipLaunchKernelGGL(k_pre, dim3(128), dim3(256), 0, stream,
                     weight, sv_W, cross_w, crossfc_w, vsdir_w, vs_W, ss_W, ws);
  hipLaunchKernelGGL(k_main, dim3(4096), dim3(256), 0, stream,
                     v_in, s_in, ws, sv_b, vs_b, ss_b, v_out, s_out);
}

// Round 3
// 450.983 us; speedup vs baseline: 2.2378x; 2.0358x over previous
//
#include <hip/hip_runtime.h>
#include <math.h>

typedef __attribute__((ext_vector_type(8))) short short8;
typedef __attribute__((ext_vector_type(4))) float floatx4;

#define EPS 1e-12f

// ws layout (u16 element offsets unless noted)
#define WS_AMAIN 0        // [400][128] rows: 0-127 W1se3, 128-255 W2se3, 256-383 vsdir,
                          //            384 colmean(W1se3), 385 colmean(W2se3), 386 ones/128, 387-399 zero
#define WS_ASCAL 51200    // [256][128] rows: 0-127 sv_W, 128-255 ss_W
#define WS_AFC   83968    // [128][256] crossfc_se3 (k: 0-127 pairs with cr, 128-255 with v2)
#define WS_AVS   116736   // [128][128] vs_W
#define WS_VDR_B 266240   // byte offset: fp32[128] rowsum(vsdir)

__device__ __forceinline__ unsigned short f2bf(float f) {
  union { float f; unsigned u; } v; v.f = f;
  unsigned r = v.u + 0x7FFFu + ((v.u >> 16) & 1u);
  return (unsigned short)(r >> 16);
}
__device__ __forceinline__ float bf2f(unsigned u16) {
  union { unsigned u; float f; } v; v.u = u16 << 16;
  return v.f;
}

__device__ __forceinline__ float block_sum_256(float v, float* red) {
  const int t = threadIdx.x;
  red[t] = v;
  __syncthreads();
  for (int s = 128; s > 0; s >>= 1) {
    if (t < s) red[t] += red[t + s];
    __syncthreads();
  }
  float r = red[0];
  __syncthreads();
  return r;
}

__global__ __launch_bounds__(256) void k_pre(
    const float* __restrict__ weight, const float* __restrict__ sv_W,
    const float* __restrict__ cross_w, const float* __restrict__ crossfc_w,
    const float* __restrict__ vsdir_w, const float* __restrict__ vs_W,
    const float* __restrict__ ss_W, unsigned short* __restrict__ wsu,
    float* __restrict__ vdr) {
  __shared__ float red[256];
  const int o = blockIdx.x;   // 128 blocks, one per output row
  const int t = threadIdx.x;  // 256

  float s1 = block_sum_256((t < 127) ? weight[o * 127 + t] : 0.f, red);
  if (t < 128)
    wsu[WS_AMAIN + o * 128 + t] = f2bf((t < 127) ? weight[o * 127 + t] : 1.f - s1);

  float s2 = block_sum_256((t < 127) ? cross_w[o * 127 + t] : 0.f, red);
  if (t < 128)
    wsu[WS_AMAIN + (128 + o) * 128 + t] = f2bf((t < 127) ? cross_w[o * 127 + t] : 1.f - s2);

  float s4 = block_sum_256((t < 128) ? vsdir_w[o * 128 + t] : 0.f, red);
  if (t < 128)
    wsu[WS_AMAIN + (256 + o) * 128 + t] = f2bf(vsdir_w[o * 128 + t]);
  if (t == 0) vdr[o] = s4;

  float s3 = block_sum_256((t < 255) ? crossfc_w[o * 255 + t] : 0.f, red);
  wsu[WS_AFC + o * 256 + t] = f2bf((t < 255) ? crossfc_w[o * 255 + t] : 1.f - s3);

  if (t < 128) {
    wsu[WS_ASCAL + o * 128 + t]         = f2bf(sv_W[o * 128 + t]);
    wsu[WS_ASCAL + (128 + o) * 128 + t] = f2bf(ss_W[o * 128 + t]);
    wsu[WS_AVS + o * 128 + t]           = f2bf(vs_W[o * 128 + t]);
  }
  if (o == 0) {
    if (t < 128) wsu[WS_AMAIN + 386 * 128 + t] = f2bf(1.f / 128.f);
    for (int l = t; l < 13 * 128; l += 256) wsu[WS_AMAIN + 387 * 128 + l] = 0;
  }
}

// colmean rows (384: W1se3, 385: W2se3) from already-written bf16 rows
__global__ void k_mean(unsigned short* __restrict__ wsu) {
  const int g = blockIdx.x, c = threadIdx.x;  // 2 blocks x 128 threads
  float s = 0.f;
  for (int o = 0; o < 128; ++o) s += bf2f(wsu[WS_AMAIN + (g * 128 + o) * 128 + c]);
  wsu[WS_AMAIN + (384 + g) * 128 + c] = f2bf(s * (1.f / 128.f));
}

// Fused MFMA kernel. Block = (b, 64 cols); wave w owns cols [w*16, w*16+16).
// All LDS B-operand arrays are [col][k] with Kpad=136; after the single staging
// barrier every LDS access is wave-private by column.
__global__ __launch_bounds__(256, 1) void k_main(
    const float* __restrict__ v_in, const float* __restrict__ s_in,
    const unsigned short* __restrict__ wsu, const float* __restrict__ vdr,
    const float* __restrict__ sv_b, const float* __restrict__ vs_b,
    const float* __restrict__ ss_b,
    float* __restrict__ v_out, float* __restrict__ s_out) {
  const int t = threadIdx.x;
  const int wave = t >> 6, lane = t & 63;
  const int q = lane >> 4, ln = lane & 15;
  const int b = blockIdx.x >> 6;
  const int n0 = (blockIdx.x & 63) * 64;
  const int mycol = wave * 16 + ln;

  __shared__ __align__(16) unsigned short xB[192 * 136];   // x; later cr
  __shared__ __align__(16) unsigned short v2B[192 * 136];  // v2
  __shared__ __align__(16) unsigned short sB[64 * 136];    // s; later sfn

  // ---- staging: global fp32 -> bf16 LDS in B layout ----
  {
    const float* vb = v_in + (size_t)b * (128 * 3 * 4096) + n0;
    for (int l = t; l < 6144; l += 256) {
      const int c = l / 48, r = l % 48;
      const int v = r >> 4, j4 = (r & 15) * 4;
      const float4 f = *(const float4*)(vb + (size_t)(c * 3 + v) * 4096 + j4);
      const int base = (v * 64 + j4) * 136 + c;
      xB[base]       = f2bf(f.x);
      xB[base + 136] = f2bf(f.y);
      xB[base + 272] = f2bf(f.z);
      xB[base + 408] = f2bf(f.w);
    }
    const float* sb = s_in + (size_t)b * (128 * 4096) + n0;
    for (int l = t; l < 2048; l += 256) {
      const int c = l >> 4, j4 = (l & 15) * 4;
      const float4 f = *(const float4*)(sb + (size_t)c * 4096 + j4);
      const int base = j4 * 136 + c;
      sB[base]       = f2bf(f.x);
      sB[base + 136] = f2bf(f.y);
      sB[base + 272] = f2bf(f.z);
      sB[base + 408] = f2bf(f.w);
    }
  }
  __syncthreads();

  // ---- g0: sv/ss GEMM (A_scal, B = s) ----
  floatx4 accS[16];
#pragma unroll
  for (int i = 0; i < 16; ++i) accS[i] = (floatx4){0.f, 0.f, 0.f, 0.f};
#pragma unroll
  for (int k = 0; k < 4; ++k) {
    const short8 bf = *(const short8*)(sB + mycol * 136 + k * 32 + q * 8);
    const unsigned short* ap = wsu + WS_ASCAL + ln * 128 + k * 32 + q * 8;
#pragma unroll
    for (int mt = 0; mt < 16; ++mt)
      accS[mt] = __builtin_amdgcn_mfma_f32_16x16x32_bf16(
          *(const short8*)(ap + mt * 2048), bf, accS[mt], 0, 0, 0);
  }
  float s2v[8][4], tssb[8][4];
  {
    float nrm = 0.f;
#pragma unroll
    for (int mt = 0; mt < 8; ++mt) {
      const float4 bb = *(const float4*)(sv_b + mt * 16 + q * 4);
      const float* bp = (const float*)&bb;
#pragma unroll
      for (int r = 0; r < 4; ++r) {
        const float tv = accS[mt][r] + bp[r];
        s2v[mt][r] = tv;
        nrm += tv * tv;
      }
    }
    nrm += __shfl_xor(nrm, 16);
    nrm += __shfl_xor(nrm, 32);
    const float inv = 1.f / fmaxf(sqrtf(nrm), EPS);
#pragma unroll
    for (int mt = 0; mt < 8; ++mt)
#pragma unroll
      for (int r = 0; r < 4; ++r) s2v[mt][r] *= inv;
#pragma unroll
    for (int mt = 0; mt < 8; ++mt) {
      const float4 b1 = *(const float4*)(ss_b + mt * 16 + q * 4);
      const float4 b2 = *(const float4*)(vs_b + mt * 16 + q * 4);
      const float* p1 = (const float*)&b1;
      const float* p2 = (const float*)&b2;
#pragma unroll
      for (int r = 0; r < 4; ++r) tssb[mt][r] = accS[8 + mt][r] + p1[r] + p2[r];
    }
  }

  // ---- g1: dd (vsdir@x) + means-row GEMM ----
  floatx4 accD[9][3];
#pragma unroll
  for (int i = 0; i < 9; ++i)
#pragma unroll
    for (int v = 0; v < 3; ++v) accD[i][v] = (floatx4){0.f, 0.f, 0.f, 0.f};
#pragma unroll
  for (int k = 0; k < 4; ++k) {
    short8 bfv[3];
#pragma unroll
    for (int v = 0; v < 3; ++v)
      bfv[v] = *(const short8*)(xB + (v * 64 + mycol) * 136 + k * 32 + q * 8);
    const unsigned short* ap = wsu + WS_AMAIN + 256 * 128 + ln * 128 + k * 32 + q * 8;
#pragma unroll
    for (int i = 0; i < 9; ++i) {
      const short8 a = *(const short8*)(ap + i * 2048);
#pragma unroll
      for (int v = 0; v < 3; ++v)
        accD[i][v] = __builtin_amdgcn_mfma_f32_16x16x32_bf16(a, bfv[v], accD[i][v], 0, 0, 0);
    }
  }
  float xm[3], vmn[3], dmn[3];
#pragma unroll
  for (int v = 0; v < 3; ++v) {
    vmn[v] = __shfl(accD[8][v][0], ln);   // row 384
    dmn[v] = __shfl(accD[8][v][1], ln);   // row 385
    xm[v]  = __shfl(accD[8][v][2], ln);   // row 386
  }

  // ---- scalar path: sfv -> sfn -> LDS (over sB) ----
  {
    float sfv[8][4];
    float ssum = 0.f;
#pragma unroll
    for (int mt = 0; mt < 8; ++mt) {
      const float4 rs4 = *(const float4*)(vdr + mt * 16 + q * 4);
      const float* rp = (const float*)&rs4;
      uint2 pk[3];
#pragma unroll
      for (int v = 0; v < 3; ++v)
        pk[v] = *(const uint2*)(xB + (v * 64 + mycol) * 136 + mt * 16 + q * 4);
#pragma unroll
      for (int r = 0; r < 4; ++r) {
        float d[3], xr[3];
#pragma unroll
        for (int v = 0; v < 3; ++v) {
          d[v] = accD[mt][v][r] - rp[r] * xm[v];
          const unsigned w = (r < 2) ? pk[v].x : pk[v].y;
          xr[v] = bf2f((w >> ((r & 1) * 16)) & 0xffffu) - xm[v];
        }
        const float n2 = d[0] * d[0] + d[1] * d[1] + d[2] * d[2];
        const float dinv = 1.f / fmaxf(sqrtf(n2), EPS);
        const float sv_ = (xr[0] * d[0] + xr[1] * d[1] + xr[2] * d[2]) * dinv;
        sfv[mt][r] = sv_;
        ssum += sv_ * sv_;
      }
    }
    ssum += __shfl_xor(ssum, 16);
    ssum += __shfl_xor(ssum, 32);
    const float sinv = 1.f / fmaxf(sqrtf(ssum), EPS);
#pragma unroll
    for (int mt = 0; mt < 8; ++mt) {
      const unsigned lo = (unsigned)f2bf(sfv[mt][0] * sinv) |
                          ((unsigned)f2bf(sfv[mt][1] * sinv) << 16);
      const unsigned hi = (unsigned)f2bf(sfv[mt][2] * sinv) |
                          ((unsigned)f2bf(sfv[mt][3] * sinv) << 16);
      *(uint2*)(sB + mycol * 136 + mt * 16 + q * 4) = make_uint2(lo, hi);
    }
  }

  // ---- g2a: v1 = W1se3@x GEMM, then v2 in-place; write v2B ----
  floatx4 accV[8][3];
#pragma unroll
  for (int i = 0; i < 8; ++i)
#pragma unroll
    for (int v = 0; v < 3; ++v) accV[i][v] = (floatx4){0.f, 0.f, 0.f, 0.f};
#pragma unroll
  for (int k = 0; k < 4; ++k) {
    short8 bfv[3];
#pragma unroll
    for (int v = 0; v < 3; ++v)
      bfv[v] = *(const short8*)(xB + (v * 64 + mycol) * 136 + k * 32 + q * 8);
    const unsigned short* ap = wsu + WS_AMAIN + ln * 128 + k * 32 + q * 8;
#pragma unroll
    for (int mt = 0; mt < 8; ++mt) {
      const short8 a = *(const short8*)(ap + mt * 2048);
#pragma unroll
      for (int v = 0; v < 3; ++v)
        accV[mt][v] = __builtin_amdgcn_mfma_f32_16x16x32_bf16(a, bfv[v], accV[mt][v], 0, 0, 0);
    }
  }
  float v2m[3];
#pragma unroll
  for (int v = 0; v < 3; ++v) {
    float s = 0.f;
#pragma unroll
    for (int mt = 0; mt < 8; ++mt)
#pragma unroll
      for (int r = 0; r < 4; ++r) {
        const float val = (accV[mt][v][r] - vmn[v]) * s2v[mt][r] + vmn[v];
        accV[mt][v][r] = val;
        s += val;
      }
    s += __shfl_xor(s, 16);
    s += __shfl_xor(s, 32);
    v2m[v] = s * (1.f / 128.f);
  }
#pragma unroll
  for (int mt = 0; mt < 8; ++mt)
#pragma unroll
    for (int v = 0; v < 3; ++v) {
      const unsigned lo = (unsigned)f2bf(accV[mt][v][0]) |
                          ((unsigned)f2bf(accV[mt][v][1]) << 16);
      const unsigned hi = (unsigned)f2bf(accV[mt][v][2]) |
                          ((unsigned)f2bf(accV[mt][v][3]) << 16);
      *(uint2*)(v2B + (v * 64 + mycol) * 136 + mt * 16 + q * 4) = make_uint2(lo, hi);
    }

  // ---- g2b: vd = W2se3@x GEMM, cross branch; write cr over xB ----
  floatx4 accW[8][3];
#pragma unroll
  for (int i = 0; i < 8; ++i)
#pragma unroll
    for (int v = 0; v < 3; ++v) accW[i][v] = (floatx4){0.f, 0.f, 0.f, 0.f};
#pragma unroll
  for (int k = 0; k < 4; ++k) {
    short8 bfv[3];
#pragma unroll
    for (int v = 0; v < 3; ++v)
      bfv[v] = *(const short8*)(xB + (v * 64 + mycol) * 136 + k * 32 + q * 8);
    const unsigned short* ap = wsu + WS_AMAIN + 128 * 128 + ln * 128 + k * 32 + q * 8;
#pragma unroll
    for (int mt = 0; mt < 8; ++mt) {
      const short8 a = *(const short8*)(ap + mt * 2048);
#pragma unroll
      for (int v = 0; v < 3; ++v)
        accW[mt][v] = __builtin_amdgcn_mfma_f32_16x16x32_bf16(a, bfv[v], accW[mt][v], 0, 0, 0);
    }
  }
  float an[8][4];
  float csum = 0.f;
#pragma unroll
  for (int mt = 0; mt < 8; ++mt)
#pragma unroll
    for (int r = 0; r < 4; ++r) {
      const float a0 = accW[mt][0][r] - dmn[0];
      const float a1 = accW[mt][1][r] - dmn[1];
      const float a2 = accW[mt][2][r] - dmn[2];
      accW[mt][0][r] = a0; accW[mt][1][r] = a1; accW[mt][2][r] = a2;
      const float n2 = a0 * a0 + a1 * a1 + a2 * a2;
      an[mt][r] = sqrtf(n2);
      csum += n2;
    }
  csum += __shfl_xor(csum, 16);
  csum += __shfl_xor(csum, 32);
  const float cninv = 1.f / fmaxf(sqrtf(csum), EPS);
#pragma unroll
  for (int mt = 0; mt < 8; ++mt) {
    float crv[3][4];
#pragma unroll
    for (int r = 0; r < 4; ++r) {
      const float sc = an[mt][r] / fmaxf(an[mt][r], EPS) * cninv;
      const float h0 = accW[mt][0][r] * sc;
      const float h1 = accW[mt][1][r] * sc;
      const float h2 = accW[mt][2][r] * sc;
      const float w0 = accV[mt][0][r], w1 = accV[mt][1][r], w2 = accV[mt][2][r];
      const float g0 = w0 - v2m[0], g1 = w1 - v2m[1], g2 = w2 - v2m[2];
      crv[0][r] = h1 * g2 - h2 * g1 + w0;
      crv[1][r] = h2 * g0 - h0 * g2 + w1;
      crv[2][r] = h0 * g1 - h1 * g0 + w2;
    }
#pragma unroll
    for (int v = 0; v < 3; ++v) {
      const unsigned lo = (unsigned)f2bf(crv[v][0]) | ((unsigned)f2bf(crv[v][1]) << 16);
      const unsigned hi = (unsigned)f2bf(crv[v][2]) | ((unsigned)f2bf(crv[v][3]) << 16);
      *(uint2*)(xB + (v * 64 + mycol) * 136 + mt * 16 + q * 4) = make_uint2(lo, hi);
    }
  }

  // ---- g3: crossfc (K=256 over [cr;v2]) + vs (K=128 over sfn) GEMMs ----
  floatx4 accO[8][3];
  floatx4 accP[8];
#pragma unroll
  for (int i = 0; i < 8; ++i) {
    accP[i] = (floatx4){0.f, 0.f, 0.f, 0.f};
#pragma unroll
    for (int v = 0; v < 3; ++v) accO[i][v] = (floatx4){0.f, 0.f, 0.f, 0.f};
  }
#pragma unroll
  for (int ks = 0; ks < 8; ++ks) {
    const unsigned short* src = (ks < 4) ? xB : v2B;
    const int kk = ks & 3;
    short8 bfv[3];
#pragma unroll
    for (int v = 0; v < 3; ++v)
      bfv[v] = *(const short8*)(src + (v * 64 + mycol) * 136 + kk * 32 + q * 8);
    const unsigned short* afc = wsu + WS_AFC + ln * 256 + ks * 32 + q * 8;
#pragma unroll
    for (int mt = 0; mt < 8; ++mt) {
      const short8 a = *(const short8*)(afc + mt * 4096);
#pragma unroll
      for (int v = 0; v < 3; ++v)
        accO[mt][v] = __builtin_amdgcn_mfma_f32_16x16x32_bf16(a, bfv[v], accO[mt][v], 0, 0, 0);
    }
    if (ks < 4) {
      const short8 bfs = *(const short8*)(sB + mycol * 136 + kk * 32 + q * 8);
      const unsigned short* avs = wsu + WS_AVS + ln * 128 + kk * 32 + q * 8;
#pragma unroll
      for (int mt = 0; mt < 8; ++mt)
        accP[mt] = __builtin_amdgcn_mfma_f32_16x16x32_bf16(
            *(const short8*)(avs + mt * 2048), bfs, accP[mt], 0, 0, 0);
    }
  }

  // ---- epilogue stores ----
  const int gc = n0 + mycol;
  float* vob = v_out + (size_t)b * (128 * 3 * 4096) + gc;
  float* sob = s_out + (size_t)b * (128 * 4096) + gc;
#pragma unroll
  for (int mt = 0; mt < 8; ++mt)
#pragma unroll
    for (int r = 0; r < 4; ++r) {
      const int o = mt * 16 + q * 4 + r;
#pragma unroll
      for (int v = 0; v < 3; ++v)
        vob[(size_t)(o * 3 + v) * 4096] = accO[mt][v][r];
      sob[(size_t)o * 4096] = accP[mt][r] + tssb[mt][r];
    }
}

extern "C" void kernel_launch(void* const* d_in, const int* in_sizes, int n_in,
                              void* d_out, int out_size, void* d_ws, size_t ws_size,
                              hipStream_t stream) {
  const float* v_in      = (const float*)d_in[0];
  const float* s_in      = (const float*)d_in[1];
  const float* weight    = (const float*)d_in[2];
  const float* sv_W      = (const float*)d_in[3];
  const float* sv_b      = (const float*)d_in[4];
  const float* cross_w   = (const float*)d_in[5];
  const float* crossfc_w = (const float*)d_in[6];
  const float* vsdir_w   = (const float*)d_in[7];
  const float* vs_W      = (const float*)d_in[8];
  const float* vs_b      = (const float*)d_in[9];
  const float* ss_W      = (const float*)d_in[10];
  const float* ss_b      = (const float*)d_in[11];

  float* out = (float*)d_out;
  float* v_out = out;                                  // [16][128][3][4096]
  float* s_out = out + (size_t)16 * 128 * 3 * 4096;    // [16][128][4096]
  unsigned short* wsu = (unsigned short*)d_ws;
  float* vdr = (float*)((char*)d_ws + WS_VDR_B);

  hipLaunchKernelGGL(k_pre, dim3(128), dim3(256), 0, stream,
                     weight, sv_W, cross_w, crossfc_w, vsdir_w, vs_W, ss_W, wsu, vdr);
  hipLaunchKernelGGL(k_mean, dim3(2), dim3(128), 0, stream, wsu);
  hipLaunchKernelGGL(k_main, dim3(1024), dim3(256), 0, stream,
                     v_in, s_in, wsu, vdr, sv_b, vs_b, ss_b, v_out, s_out);
}